// Round 13
// baseline (1146.090 us; speedup 1.0000x reference)
//
#include <hip/hip_runtime.h>
#include <hip/hip_bf16.h>

// LIF fused kernel, Round 16: R15 with codegen overhead squeezed out.
//
// R15 post-mortem: VALU-issue-bound (70.6% busy = 663 cy/t vs MFMA 206,
// idle ~70). Measured ~82 VALU inst/wave/t vs ~45 static -> ~half is
// addressing/loop overhead (slot-index math, 64-bit load addressing,
// b64+cndmask select, unfused combine; VGPR=28 shows rematerialization).
//
// R16 changes (arithmetic untouched -> output bit-identical, absmax
// exactly 0.0078125):
//  1. 4t-unrolled loop, 2 barriers/iter: xq slot indices become literals
//     0..3 -> LDS ops get immediate offset folding; all &3 math gone.
//     Phase A: LIF(t-2,t-1)=slots 2,3; produce t->0, t+1->1; barrier.
//     Phase B: LIF(t,t+1)=slots 0,1; produce t+2->2, t+3->3; barrier.
//  2. b32 bits loads (dword = wq*2+(lq>>1), half by lq&1; R14-proven) --
//     kills per-t cndmask, halves bits traffic.
//  3. combine as ((a0<<8)+a1)<<8)+a2 -> 2x v_lshl_add_u32.
//
// Packed layout: bits[t*4096 + b*16 + wd], bit j (LSB) = spike[t][b][wd*32+j].

typedef __attribute__((ext_vector_type(8))) short short8;   // 8 x bf16
typedef __attribute__((ext_vector_type(4))) float floatx4;
typedef __attribute__((ext_vector_type(2))) unsigned uintx2;
typedef __attribute__((ext_vector_type(4))) int int4v;

#define T_STEPS 1024
#define B_DIM   256
#define F_DIM   512
#define BF      (B_DIM * F_DIM)
#define ROWP    520   // (fallback kernel only)

static __device__ __forceinline__ unsigned short f2bf_rne(float f) {
    unsigned u = __float_as_uint(f);
    return (unsigned short)((u + 0x7FFFu + ((u >> 16) & 1u)) >> 16);
}
static __device__ __forceinline__ float bf2f(unsigned short h) {
    return __uint_as_float(((unsigned)h) << 16);
}

// ---------------- prepass: fp32 {0,1} -> bitmask ----------------
__global__ __launch_bounds__(256)
void pack_kernel(const float* __restrict__ sp, unsigned* __restrict__ bits)
{
    const int lane = threadIdx.x & 63;
    const int wv   = blockIdx.x * 4 + (threadIdx.x >> 6);
    for (int c = wv; c < 65536; c += 2048 * 4) {
        const float* p = sp + (size_t)c * 2048;
        unsigned val = 0;
        #pragma unroll
        for (int r = 0; r < 32; ++r) {
            float x = p[r * 64 + lane];
            unsigned long long m = __ballot(x != 0.0f);
            unsigned sel = (lane & 1) ? (unsigned)(m >> 32) : (unsigned)m;
            if ((lane >> 1) == r) val = sel;
        }
        bits[(size_t)c * 64 + lane] = val;
    }
}

// -------- main kernel: i8 engine, 4t-unrolled, balanced 4-way finisher --
__global__ __launch_bounds__(512, 4)
void lif_kernel_bits(const unsigned* __restrict__ bits,
                     const float* __restrict__ W,
                     float* __restrict__ out)
{
    __shared__ int   xq[4][8 * 256];   // [slot 0..3][wq*256 + lane*4 + r]
    __shared__ float rowmax[8][16];    // setup-only
    __shared__ float rowinv[16];       // per-g-row invC broadcast

    const int tid  = threadIdx.x;
    const int lane = tid & 63;
    const int wq   = tid >> 6;          // 0..7: K-eighth, k in [wq*64, +64)
    const int bt   = blockIdx.x & 15;
    const int gb   = blockIdx.x >> 4;   // 0..31
    const int b0   = bt * 16;
    const int gw   = gb * 16;
    const int mrow = lane & 15;
    const int lq   = lane >> 4;         // 0..3: k-chunk of 16 within the 64

    // ---- W setup (once): rows gw+mrow, k = wq*64 + lq*16 + j  [R15 code]
    int4v wi0, wi1, wi2;
    {
        const float* wp = W + (size_t)(gw + mrow) * F_DIM + wq * 64 + lq * 16;
        float wv[16];
        float lm = 0.0f;
        #pragma unroll
        for (int j = 0; j < 16; ++j) {
            wv[j] = wp[j];
            lm = fmaxf(lm, fabsf(wv[j]));
        }
        lm = fmaxf(lm, __shfl_xor(lm, 16, 64));
        lm = fmaxf(lm, __shfl_xor(lm, 32, 64));
        if (lane < 16) rowmax[wq][lane] = lm;
        __syncthreads();
        float S = 1e-30f;
        #pragma unroll
        for (int w8 = 0; w8 < 8; ++w8) S = fmaxf(S, rowmax[w8][mrow]);
        __syncthreads();   // rowmax consumed
        const float C = 8000000.0f / S;
        if (wq == 0 && lane < 16) rowinv[lane] = S / 8000000.0f;
        #pragma unroll
        for (int d = 0; d < 4; ++d) {
            unsigned p0 = 0, p1 = 0, p2 = 0;
            #pragma unroll
            for (int jj = 0; jj < 4; ++jj) {
                int q  = __float2int_rn(wv[d * 4 + jj] * C);
                int d2 = (q << 24) >> 24;          // sext low byte
                int r1 = (q - d2) >> 8;            // exact (divisible)
                int d1 = (r1 << 24) >> 24;
                int d0 = (r1 - d1) >> 8;           // |d0| <= 123
                p0 |= (unsigned)(d0 & 0xFF) << (8 * jj);
                p1 |= (unsigned)(d1 & 0xFF) << (8 * jj);
                p2 |= (unsigned)(d2 & 0xFF) << (8 * jj);
            }
            wi0[d] = (int)p0; wi1[d] = (int)p1; wi2[d] = (int)p2;
        }
    }
    __syncthreads();   // rowinv ready (before any xq activity)

    // ---- LIF state: 4-way finisher, one wave per SIMD. Wave wq (0..3)
    // owns flat neuron j = wq*64 + lane: b = b0+wq*4+(lane&3),
    // g = gw+(lane>>2).
    const bool  fin   = (wq < 4);
    const float myInv = rowinv[lane >> 2];   // used by finishers only
    float v0 = 0.f, c0 = 0.f, z0 = 0.f;

    // bits: one b32/lane/t. dword = row*16 + wq*2 + (lq>>1); half by lq&1.
    const unsigned* bp = bits + (size_t)(b0 + mrow) * 16 + wq * 2 + (lq >> 1);
    const int hsh = (lq & 1) * 16;

    auto ldbits = [&](int t) -> unsigned {
        return bp[(size_t)t * 4096];
    };

    // expand 16 bits -> 16 i8 bytes {0,1}: nibble * 0x204081 spreads bit j
    // to byte j (no carries); mask keeps LSBs.
    auto expand = [&](unsigned dw) -> int4v {
        unsigned h16 = dw >> hsh;
        int4v a;
        #pragma unroll
        for (int d = 0; d < 4; ++d) {
            unsigned b4 = (h16 >> (4 * d)) & 0xFu;
            a[d] = (int)((b4 * 0x00204081u) & 0x01010101u);
        }
        return a;
    };

    const int4v iz = {0, 0, 0, 0};

    // 3 exact-int MFMAs + exact-int combine (2x v_lshl_add per element)
    auto mci = [&](int4v aI) -> int4v {
        int4v a0 = __builtin_amdgcn_mfma_i32_16x16x64_i8(aI, wi0, iz, 0, 0, 0);
        int4v a1 = __builtin_amdgcn_mfma_i32_16x16x64_i8(aI, wi1, iz, 0, 0, 0);
        int4v a2 = __builtin_amdgcn_mfma_i32_16x16x64_i8(aI, wi2, iz, 0, 0, 0);
        int4v c;
        #pragma unroll
        for (int r = 0; r < 4; ++r)
            c[r] = (((a0[r] << 8) + a1[r]) << 8) + a2[r];
        return c;
    };

    // finisher: dense conflict-free reads (4B lane stride), exact-int sum,
    // 1 cvt, LIF
    auto lif1 = [&](const int* xs) {
        const int* p = xs + wq * 64 + lane;
        int s = 0;
        #pragma unroll
        for (int w8 = 0; w8 < 8; ++w8)
            s += p[w8 * 256];
        float x  = (float)s * myInv;
        float vd = v0 + 0.1f * ((0.0f - v0) + c0);   // DT*TAU_MEM_INV
        float id = c0 - 0.2f * c0;                    // DT*TAU_SYN_INV
        bool  sp = (vd - 1.0f) > 0.0f;                // heaviside
        z0 = sp ? 1.0f : 0.0f;
        v0 = sp ? 0.0f : vd;                          // V_RESET = 0
        c0 = id + x;
    };

    unsigned q0 = ldbits(0), q1 = ldbits(1), q2 = ldbits(2), q3 = ldbits(3);

    for (int t = 0; t < T_STEPS; t += 4) {
        // ---- Phase A: LIF(t-2),LIF(t-1) from slots 2,3 (written prev
        // Phase B, barrier-ordered); produce M(t)->slot0, M(t+1)->slot1
        // (slots last read prev Phase B). LIF FIRST for pipe diversity.
        if (fin && t > 0) {
            lif1(&xq[2][0]);
            lif1(&xq[3][0]);
        }
        {
            int4v cA = mci(expand(q0));
            *(int4v*)&xq[0][wq * 256 + lane * 4] = cA;
            int4v cB = mci(expand(q1));
            *(int4v*)&xq[1][wq * 256 + lane * 4] = cB;
        }
        if (t + 4 < T_STEPS) {
            q0 = ldbits(t + 4);
            q1 = ldbits(t + 5);
        }
        __syncthreads();   // slots 0,1 ready; reads of 2,3 done

        // ---- Phase B: LIF(t),LIF(t+1) from slots 0,1; produce
        // M(t+2)->slot2, M(t+3)->slot3 (read in Phase A, barrier-ordered).
        if (fin) {
            lif1(&xq[0][0]);
            lif1(&xq[1][0]);
        }
        {
            int4v cC = mci(expand(q2));
            *(int4v*)&xq[2][wq * 256 + lane * 4] = cC;
            int4v cD = mci(expand(q3));
            *(int4v*)&xq[3][wq * 256 + lane * 4] = cD;
        }
        if (t + 6 < T_STEPS) {
            q2 = ldbits(t + 6);
            q3 = ldbits(t + 7);
        }
        __syncthreads();   // slots 2,3 ready; reads of 0,1 done
    }
    // epilogue: LIF(1022), LIF(1023) from slots 2,3 (barrier was last stmt)
    if (fin) {
        lif1(&xq[2][0]);
        lif1(&xq[3][0]);
        const size_t idx = (size_t)(b0 + wq * 4 + (lane & 3)) * F_DIM
                         + gw + (lane >> 2);
        out[idx]          = z0;
        out[BF + idx]     = v0;
        out[2 * BF + idx] = c0;
    }
}

// ---------------- fallback: R3 fp32-input kernel (verified) ----------------
__global__ __launch_bounds__(256, 1)
void lif_kernel_f32(const float* __restrict__ spikes,
                    const float* __restrict__ W,
                    float* __restrict__ out)
{
    __shared__ unsigned short sAf[16 * ROWP];
    __shared__ float xbuf[2 * 256];

    const int tid  = threadIdx.x;
    const int lane = tid & 63;
    const int w    = tid >> 6;
    const int gh   = w & 1;
    const int kh   = w >> 1;
    const int bt   = blockIdx.x & 15;
    const int gb   = blockIdx.x >> 4;
    const int b0   = bt * 16;
    const int gw   = gb * 32 + gh * 16;
    const int mrow = lane & 15;
    const int kq   = lane >> 4;

    short8 whi[8], wmd[8], wlo[8];
    {
        const float* wp = W + (size_t)(gw + mrow) * F_DIM + kh * 256 + kq * 8;
        #pragma unroll
        for (int ks = 0; ks < 8; ++ks) {
            short8 hi, md, lo;
            #pragma unroll
            for (int j = 0; j < 8; ++j) {
                float f = wp[ks * 32 + j];
                unsigned short h = f2bf_rne(f);
                float r1 = f - bf2f(h);
                unsigned short m = f2bf_rne(r1);
                float r2 = r1 - bf2f(m);
                hi[j] = (short)h;
                md[j] = (short)m;
                lo[j] = (short)f2bf_rne(r2);
            }
            whi[ks] = hi; wmd[ks] = md; wlo[ks] = lo;
        }
    }

    float v[4]  = {0.f, 0.f, 0.f, 0.f};
    float cu[4] = {0.f, 0.f, 0.f, 0.f};
    float zf[4] = {0.f, 0.f, 0.f, 0.f};

    floatx4 ld[8];
    auto issue_loads = [&](int t) {
        const floatx4* sp = (const floatx4*)(spikes + (size_t)t * BF + (size_t)b0 * F_DIM);
        #pragma unroll
        for (int j = 0; j < 8; ++j)
            ld[j] = sp[tid + 256 * j];
    };

    issue_loads(0);
    for (int t = 0; t < T_STEPS; ++t) {
        #pragma unroll
        for (int j = 0; j < 8; ++j) {
            const int q = tid + 256 * j;
            const int row = q >> 7, col4 = q & 127;
            unsigned u0 = __float_as_uint(ld[j][0]);
            unsigned u1 = __float_as_uint(ld[j][1]);
            unsigned u2 = __float_as_uint(ld[j][2]);
            unsigned u3 = __float_as_uint(ld[j][3]);
            uintx2 d;
            d[0] = (u0 >> 16) | (u1 & 0xFFFF0000u);
            d[1] = (u2 >> 16) | (u3 & 0xFFFF0000u);
            *(uintx2*)&sAf[row * ROWP + col4 * 4] = d;
        }
        __syncthreads();
        if (t + 1 < T_STEPS) issue_loads(t + 1);

        floatx4 ah = {0.f, 0.f, 0.f, 0.f};
        floatx4 am = {0.f, 0.f, 0.f, 0.f};
        floatx4 al = {0.f, 0.f, 0.f, 0.f};
        const unsigned short* arow = &sAf[mrow * ROWP + kh * 256 + kq * 8];
        #pragma unroll
        for (int ks = 0; ks < 8; ++ks) {
            short8 a = *(const short8*)(arow + ks * 32);
            ah = __builtin_amdgcn_mfma_f32_16x16x32_bf16(a, whi[ks], ah, 0, 0, 0);
            am = __builtin_amdgcn_mfma_f32_16x16x32_bf16(a, wmd[ks], am, 0, 0, 0);
            al = __builtin_amdgcn_mfma_f32_16x16x32_bf16(a, wlo[ks], al, 0, 0, 0);
        }

        if (kh == 1) {
            floatx4 xp = (ah + am) + al;
            *(floatx4*)&xbuf[gh * 256 + lane * 4] = xp;
        }
        __syncthreads();
        if (kh == 0) {
            floatx4 other = *(const floatx4*)&xbuf[gh * 256 + lane * 4];
            #pragma unroll
            for (int r = 0; r < 4; ++r) {
                float x    = ((ah[r] + am[r]) + al[r]) + other[r];
                float vdec = v[r] + 0.1f * ((0.0f - v[r]) + cu[r]);
                float idec = cu[r] - 0.2f * cu[r];
                bool  spk  = (vdec - 1.0f) > 0.0f;
                zf[r] = spk ? 1.0f : 0.0f;
                v[r]  = spk ? 0.0f : vdec;
                cu[r] = idec + x;
            }
        }
    }

    if (kh == 0) {
        #pragma unroll
        for (int r = 0; r < 4; ++r) {
            const size_t idx = (size_t)(b0 + kq * 4 + r) * F_DIM + gw + mrow;
            out[idx]          = zf[r];
            out[BF + idx]     = v[r];
            out[2 * BF + idx] = cu[r];
        }
    }
}

extern "C" void kernel_launch(void* const* d_in, const int* in_sizes, int n_in,
                              void* d_out, int out_size, void* d_ws, size_t ws_size,
                              hipStream_t stream)
{
    const float* spikes = (const float*)d_in[0];   // [T,B,F] fp32
    const float* W      = (const float*)d_in[1];   // [F,F]   fp32
    float* out          = (float*)d_out;           // [3,B,F] fp32

    const size_t need_bits = (size_t)T_STEPS * B_DIM * (F_DIM / 8);   // 16 MiB

    if (d_ws != nullptr && ws_size >= need_bits) {
        unsigned* bits = (unsigned*)d_ws;
        pack_kernel<<<dim3(2048), dim3(256), 0, stream>>>(spikes, bits);
        lif_kernel_bits<<<dim3(512), dim3(512), 0, stream>>>(bits, W, out);
    } else {
        lif_kernel_f32<<<dim3(256), dim3(256), 0, stream>>>(spikes, W, out);
    }
}

// Round 15
// 1042.741 us; speedup vs baseline: 1.0991x; 1.0991x over previous
//
#include <hip/hip_runtime.h>
#include <hip/hip_bf16.h>

// LIF fused kernel, Round 18 (= R17 resubmit; R17 bench was an infra
// failure: "MI355X container failed twice", no counters. Source re-audited
// against verified R15 -- only the early-issue load hoist differs; clean.)
//
// R16 post-mortem: literal-slot/b32 "codegen" rewrite REGRESSED (400->490:
// VALUBusy 70.6->53, MfmaUtil 22->17.5 -- added stall, not saved work).
// Reverted wholesale.
//
// R17/R18's single change (T14 issue-early): R15 issued the next-pair bits
// loads right before __syncthreads(); the compiler's s_waitcnt vmcnt(0)
// before s_barrier drains them -> all 8 waves stall ~200cy (L2 round trip)
// per 2t with nothing under it (~100 cy/t idle, matching R15's unexplained
// residual). Now loads are issued at the TOP of the body into fresh regs
// (n0,n1); lif + expand + 6 MFMA + ds_writes (~500cy) hide the latency
// before the barrier drain. Arithmetic byte-identical to R15 -> absmax
// exactly 0.0078125.
//
// Packed layout: bits[t*4096 + b*16 + wd], bit j (LSB) = spike[t][b][wd*32+j].

typedef __attribute__((ext_vector_type(8))) short short8;   // 8 x bf16
typedef __attribute__((ext_vector_type(4))) float floatx4;
typedef __attribute__((ext_vector_type(2))) unsigned uintx2;
typedef __attribute__((ext_vector_type(4))) int int4v;

#define T_STEPS 1024
#define B_DIM   256
#define F_DIM   512
#define BF      (B_DIM * F_DIM)
#define ROWP    520   // (fallback kernel only)

static __device__ __forceinline__ unsigned short f2bf_rne(float f) {
    unsigned u = __float_as_uint(f);
    return (unsigned short)((u + 0x7FFFu + ((u >> 16) & 1u)) >> 16);
}
static __device__ __forceinline__ float bf2f(unsigned short h) {
    return __uint_as_float(((unsigned)h) << 16);
}

// ---------------- prepass: fp32 {0,1} -> bitmask ----------------
__global__ __launch_bounds__(256)
void pack_kernel(const float* __restrict__ sp, unsigned* __restrict__ bits)
{
    const int lane = threadIdx.x & 63;
    const int wv   = blockIdx.x * 4 + (threadIdx.x >> 6);
    for (int c = wv; c < 65536; c += 2048 * 4) {
        const float* p = sp + (size_t)c * 2048;
        unsigned val = 0;
        #pragma unroll
        for (int r = 0; r < 32; ++r) {
            float x = p[r * 64 + lane];
            unsigned long long m = __ballot(x != 0.0f);
            unsigned sel = (lane & 1) ? (unsigned)(m >> 32) : (unsigned)m;
            if ((lane >> 1) == r) val = sel;
        }
        bits[(size_t)c * 64 + lane] = val;
    }
}

// -------- main kernel: i8 engine, int xq, 2t/barrier, 4-way finisher ----
__global__ __launch_bounds__(512, 4)
void lif_kernel_bits(const unsigned* __restrict__ bits,
                     const float* __restrict__ W,
                     float* __restrict__ out)
{
    __shared__ int   xq[4][8 * 256];   // [t&3][wq*256 + lane*4 + r] int partials
    __shared__ float rowmax[8][16];    // setup-only
    __shared__ float rowinv[16];       // per-g-row invC broadcast

    const int tid  = threadIdx.x;
    const int lane = tid & 63;
    const int wq   = tid >> 6;          // 0..7: K-eighth, k in [wq*64, +64)
    const int bt   = blockIdx.x & 15;
    const int gb   = blockIdx.x >> 4;   // 0..31
    const int b0   = bt * 16;
    const int gw   = gb * 16;
    const int mrow = lane & 15;
    const int lq   = lane >> 4;         // 0..3: k-chunk of 16 within the 64

    // ---- W setup (once): rows gw+mrow, k = wq*64 + lq*16 + j  [R15 code]
    int4v wi0, wi1, wi2;
    {
        const float* wp = W + (size_t)(gw + mrow) * F_DIM + wq * 64 + lq * 16;
        float wv[16];
        float lm = 0.0f;
        #pragma unroll
        for (int j = 0; j < 16; ++j) {
            wv[j] = wp[j];
            lm = fmaxf(lm, fabsf(wv[j]));
        }
        lm = fmaxf(lm, __shfl_xor(lm, 16, 64));
        lm = fmaxf(lm, __shfl_xor(lm, 32, 64));
        if (lane < 16) rowmax[wq][lane] = lm;
        __syncthreads();
        float S = 1e-30f;
        #pragma unroll
        for (int w8 = 0; w8 < 8; ++w8) S = fmaxf(S, rowmax[w8][mrow]);
        __syncthreads();   // rowmax consumed
        const float C = 8000000.0f / S;
        if (wq == 0 && lane < 16) rowinv[lane] = S / 8000000.0f;
        #pragma unroll
        for (int d = 0; d < 4; ++d) {
            unsigned p0 = 0, p1 = 0, p2 = 0;
            #pragma unroll
            for (int jj = 0; jj < 4; ++jj) {
                int q  = __float2int_rn(wv[d * 4 + jj] * C);
                int d2 = (q << 24) >> 24;          // sext low byte
                int r1 = (q - d2) >> 8;            // exact (divisible)
                int d1 = (r1 << 24) >> 24;
                int d0 = (r1 - d1) >> 8;           // |d0| <= 123
                p0 |= (unsigned)(d0 & 0xFF) << (8 * jj);
                p1 |= (unsigned)(d1 & 0xFF) << (8 * jj);
                p2 |= (unsigned)(d2 & 0xFF) << (8 * jj);
            }
            wi0[d] = (int)p0; wi1[d] = (int)p1; wi2[d] = (int)p2;
        }
    }
    __syncthreads();   // rowinv ready (before any xq activity)

    // ---- LIF state: 4-way finisher, one wave per SIMD. Wave wq (0..3)
    // owns flat neuron j = wq*64 + lane: b = b0+wq*4+(lane&3),
    // g = gw+(lane>>2). invC for that g-row from the broadcast table.
    const bool  fin   = (wq < 4);
    const float myInv = rowinv[lane >> 2];   // used by finishers only
    float v0 = 0.f, c0 = 0.f, z0 = 0.f;

    // bits source: row b0+mrow, dwords wq*2, wq*2+1 (8B aligned)  [R15]
    const unsigned* bp = bits + (size_t)(b0 + mrow) * 16 + wq * 2;  // +4096/t

    auto ldbits = [&](int t) -> uintx2 {
        return *(const uintx2*)(bp + (size_t)t * 4096);
    };

    // expand 16 bits -> 16 i8 bytes {0,1}: nibble * 0x204081 spreads bit j
    // to byte j (no carries); mask keeps LSBs.  [R15]
    auto expand = [&](uintx2 bq) -> int4v {
        unsigned h16 = ((lq & 2) ? bq[1] : bq[0]) >> ((lq & 1) * 16);
        int4v a;
        #pragma unroll
        for (int d = 0; d < 4; ++d) {
            unsigned b4 = (h16 >> (4 * d)) & 0xFu;
            a[d] = (int)((b4 * 0x00204081u) & 0x01010101u);
        }
        return a;
    };

    const int4v iz = {0, 0, 0, 0};

    // 3 exact-int MFMAs + exact-int combine (|c| <= 5.2e8)  [R15]
    auto mci = [&](int4v aI) -> int4v {
        int4v a0 = __builtin_amdgcn_mfma_i32_16x16x64_i8(aI, wi0, iz, 0, 0, 0);
        int4v a1 = __builtin_amdgcn_mfma_i32_16x16x64_i8(aI, wi1, iz, 0, 0, 0);
        int4v a2 = __builtin_amdgcn_mfma_i32_16x16x64_i8(aI, wi2, iz, 0, 0, 0);
        int4v c;
        #pragma unroll
        for (int r = 0; r < 4; ++r)
            c[r] = ((a0[r] << 16) + (a1[r] << 8)) + a2[r];
        return c;
    };

    // finisher: dense conflict-free reads (4B lane stride), exact-int sum,
    // 1 cvt, LIF  [R15]
    auto lif1 = [&](const int* xs) {
        const int* p = xs + wq * 64 + lane;
        int s = 0;
        #pragma unroll
        for (int w8 = 0; w8 < 8; ++w8)
            s += p[w8 * 256];
        float x  = (float)s * myInv;
        float vd = v0 + 0.1f * ((0.0f - v0) + c0);   // DT*TAU_MEM_INV
        float id = c0 - 0.2f * c0;                    // DT*TAU_SYN_INV
        bool  sp = (vd - 1.0f) > 0.0f;                // heaviside
        z0 = sp ? 1.0f : 0.0f;
        v0 = sp ? 0.0f : vd;                          // V_RESET = 0
        c0 = id + x;
    };

    uintx2 q0 = ldbits(0);
    uintx2 q1 = ldbits(1);

    for (int t = 0; t < T_STEPS; t += 2) {
        // ---- EARLY ISSUE (the R17/R18 change): next-pair loads go out
        // first so the ~200cy L2 latency hides under lif+expand+MFMA+
        // ds_writes instead of being exposed at the barrier's vmcnt(0)
        // drain.
        uintx2 n0 = q0, n1 = q1;
        if (t + 2 < T_STEPS) {
            n0 = ldbits(t + 2);
            n1 = ldbits(t + 3);
        }
        // deferred LIF(t-2), LIF(t-1): slots (t+2)&3, (t+3)&3 -- these are
        // overwritten only NEXT iteration (after the barrier). LIF FIRST:
        // finisher waves run VALU while producer waves hit the matrix pipe.
        if (fin && t > 0) {
            lif1(&xq[(t + 2) & 3][0]);
            lif1(&xq[(t + 3) & 3][0]);
        }
        // produce M(t) -> slot t&3, M(t+1) -> slot (t+1)&3 (b128 writes)
        {
            int4v cA = mci(expand(q0));
            *(int4v*)&xq[t & 3][wq * 256 + lane * 4] = cA;
            int4v cB = mci(expand(q1));
            *(int4v*)&xq[(t + 1) & 3][wq * 256 + lane * 4] = cB;
        }
        q0 = n0;
        q1 = n1;
        __syncthreads();   // slots t,t+1 ready; reads of t-2,t-1 done
    }
    // epilogue: LIF(1022) slot 2, LIF(1023) slot 3 (barrier was last stmt)
    if (fin) {
        lif1(&xq[2][0]);
        lif1(&xq[3][0]);
        const size_t idx = (size_t)(b0 + wq * 4 + (lane & 3)) * F_DIM
                         + gw + (lane >> 2);
        out[idx]          = z0;
        out[BF + idx]     = v0;
        out[2 * BF + idx] = c0;
    }
}

// ---------------- fallback: R3 fp32-input kernel (verified) ----------------
__global__ __launch_bounds__(256, 1)
void lif_kernel_f32(const float* __restrict__ spikes,
                    const float* __restrict__ W,
                    float* __restrict__ out)
{
    __shared__ unsigned short sAf[16 * ROWP];
    __shared__ float xbuf[2 * 256];

    const int tid  = threadIdx.x;
    const int lane = tid & 63;
    const int w    = tid >> 6;
    const int gh   = w & 1;
    const int kh   = w >> 1;
    const int bt   = blockIdx.x & 15;
    const int gb   = blockIdx.x >> 4;
    const int b0   = bt * 16;
    const int gw   = gb * 32 + gh * 16;
    const int mrow = lane & 15;
    const int kq   = lane >> 4;

    short8 whi[8], wmd[8], wlo[8];
    {
        const float* wp = W + (size_t)(gw + mrow) * F_DIM + kh * 256 + kq * 8;
        #pragma unroll
        for (int ks = 0; ks < 8; ++ks) {
            short8 hi, md, lo;
            #pragma unroll
            for (int j = 0; j < 8; ++j) {
                float f = wp[ks * 32 + j];
                unsigned short h = f2bf_rne(f);
                float r1 = f - bf2f(h);
                unsigned short m = f2bf_rne(r1);
                float r2 = r1 - bf2f(m);
                hi[j] = (short)h;
                md[j] = (short)m;
                lo[j] = (short)f2bf_rne(r2);
            }
            whi[ks] = hi; wmd[ks] = md; wlo[ks] = lo;
        }
    }

    float v[4]  = {0.f, 0.f, 0.f, 0.f};
    float cu[4] = {0.f, 0.f, 0.f, 0.f};
    float zf[4] = {0.f, 0.f, 0.f, 0.f};

    floatx4 ld[8];
    auto issue_loads = [&](int t) {
        const floatx4* sp = (const floatx4*)(spikes + (size_t)t * BF + (size_t)b0 * F_DIM);
        #pragma unroll
        for (int j = 0; j < 8; ++j)
            ld[j] = sp[tid + 256 * j];
    };

    issue_loads(0);
    for (int t = 0; t < T_STEPS; ++t) {
        #pragma unroll
        for (int j = 0; j < 8; ++j) {
            const int q = tid + 256 * j;
            const int row = q >> 7, col4 = q & 127;
            unsigned u0 = __float_as_uint(ld[j][0]);
            unsigned u1 = __float_as_uint(ld[j][1]);
            unsigned u2 = __float_as_uint(ld[j][2]);
            unsigned u3 = __float_as_uint(ld[j][3]);
            uintx2 d;
            d[0] = (u0 >> 16) | (u1 & 0xFFFF0000u);
            d[1] = (u2 >> 16) | (u3 & 0xFFFF0000u);
            *(uintx2*)&sAf[row * ROWP + col4 * 4] = d;
        }
        __syncthreads();
        if (t + 1 < T_STEPS) issue_loads(t + 1);

        floatx4 ah = {0.f, 0.f, 0.f, 0.f};
        floatx4 am = {0.f, 0.f, 0.f, 0.f};
        floatx4 al = {0.f, 0.f, 0.f, 0.f};
        const unsigned short* arow = &sAf[mrow * ROWP + kh * 256 + kq * 8];
        #pragma unroll
        for (int ks = 0; ks < 8; ++ks) {
            short8 a = *(const short8*)(arow + ks * 32);
            ah = __builtin_amdgcn_mfma_f32_16x16x32_bf16(a, whi[ks], ah, 0, 0, 0);
            am = __builtin_amdgcn_mfma_f32_16x16x32_bf16(a, wmd[ks], am, 0, 0, 0);
            al = __builtin_amdgcn_mfma_f32_16x16x32_bf16(a, wlo[ks], al, 0, 0, 0);
        }

        if (kh == 1) {
            floatx4 xp = (ah + am) + al;
            *(floatx4*)&xbuf[gh * 256 + lane * 4] = xp;
        }
        __syncthreads();
        if (kh == 0) {
            floatx4 other = *(const floatx4*)&xbuf[gh * 256 + lane * 4];
            #pragma unroll
            for (int r = 0; r < 4; ++r) {
                float x    = ((ah[r] + am[r]) + al[r]) + other[r];
                float vdec = v[r] + 0.1f * ((0.0f - v[r]) + cu[r]);
                float idec = cu[r] - 0.2f * cu[r];
                bool  spk  = (vdec - 1.0f) > 0.0f;
                zf[r] = spk ? 1.0f : 0.0f;
                v[r]  = spk ? 0.0f : vdec;
                cu[r] = idec + x;
            }
        }
    }

    if (kh == 0) {
        #pragma unroll
        for (int r = 0; r < 4; ++r) {
            const size_t idx = (size_t)(b0 + kq * 4 + r) * F_DIM + gw + mrow;
            out[idx]          = zf[r];
            out[BF + idx]     = v[r];
            out[2 * BF + idx] = cu[r];
        }
    }
}

extern "C" void kernel_launch(void* const* d_in, const int* in_sizes, int n_in,
                              void* d_out, int out_size, void* d_ws, size_t ws_size,
                              hipStream_t stream)
{
    const float* spikes = (const float*)d_in[0];   // [T,B,F] fp32
    const float* W      = (const float*)d_in[1];   // [F,F]   fp32
    float* out          = (float*)d_out;           // [3,B,F] fp32

    const size_t need_bits = (size_t)T_STEPS * B_DIM * (F_DIM / 8);   // 16 MiB

    if (d_ws != nullptr && ws_size >= need_bits) {
        unsigned* bits = (unsigned*)d_ws;
        pack_kernel<<<dim3(2048), dim3(256), 0, stream>>>(spikes, bits);
        lif_kernel_bits<<<dim3(512), dim3(512), 0, stream>>>(bits, W, out);
    } else {
        lif_kernel_f32<<<dim3(256), dim3(256), 0, stream>>>(spikes, W, out);
    }
}